// Round 11
// baseline (32.090 us; speedup 1.0000x reference)
//
#include <hip/hip_runtime.h>

#define IMG_H 1024
#define IMG_W 1024
#define NIMG  16
#define NPIX  16777216.0f   // 16*1024*1024
#define NBLK  2048          // 128 8-row strips per image
#define LOG2E 1.44269504088896340736f
#define LN2   0.69314718055994530942f

#ifndef __has_builtin
#define __has_builtin(x) 0
#endif

// Async global->LDS, 16B per lane, zero VGPR cost. dstLds must be the
// WAVE-UNIFORM base; HW adds lane*16. src is the per-lane global address.
__device__ __forceinline__ void stage16(const float* src, float* dstLds, int lane) {
#if __has_builtin(__builtin_amdgcn_global_load_lds)
    __builtin_amdgcn_global_load_lds(
        (const __attribute__((address_space(1))) void*)src,
        (__attribute__((address_space(3))) void*)dstLds,
        16, 0, 0);
#else
    *reinterpret_cast<float4*>(dstLds + (lane << 2)) =
        *reinterpret_cast<const float4*>(src);
#endif
}

// ws layout: one float4 per block {bce, inter, sum_p, sum_t}. 2048*16B = 32 KB.

__global__ __launch_bounds__(256, 4) void dal_main(
    const float* __restrict__ xlogits,
    const float* __restrict__ gmask,
    const float* __restrict__ fuse,
    float4* __restrict__ ws4)
{
    __shared__ float lds[10 * 1024];    // 40960 B: mask rows r0-1 .. r0+8

    const int b    = blockIdx.x;
    const int img  = b >> 7;            // 128 blocks per image
    const int r0   = (b & 127) << 3;    // rows r0 .. r0+7, r0 % 8 == 0
    const int tid  = (int)threadIdx.x;
    const int wid  = tid >> 6;
    const int lane = tid & 63;
    const int j0   = tid * 4;

    const float w0 = fuse[0], w1 = fuse[1], w2 = fuse[2];

    const size_t ibase = (size_t)img * (IMG_H * IMG_W);
    const float* gi = gmask + ibase;
    const float* xi = xlogits + ibase;

    // ---- stage ALL 10 mask rows async (no VGPR round trip; all in flight)
    #pragma unroll
    for (int t = 0; t < 10; ++t) {
        int r  = r0 - 1 + t;
        int rc = r < 0 ? 0 : (r > IMG_H - 1 ? IMG_H - 1 : r);  // clamped; pad fixed later
        stage16(gi + (size_t)rc * IMG_W + j0, &lds[t * 1024 + (wid << 8)], lane);
    }

    // ---- logits loads (independent; drained by the same barrier)
    float4 xv[8];
    const float* xr = xi + (size_t)r0 * IMG_W + j0;
    #pragma unroll
    for (int r = 0; r < 8; ++r)
        xv[r] = *reinterpret_cast<const float4*>(xr + (size_t)r * IMG_W);

    __syncthreads();   // vmcnt(0) + barrier: LDS tiles + xv all resident

    // ---- fold rows from LDS: rowmin over (j0+k-1 .. j0+k+1) + center values
    const bool hasL = (j0 > 0);
    const bool hasR = (j0 + 4 < IMG_W);
    const int  jl   = hasL ? j0 - 1 : 0;
    const int  jr   = hasR ? j0 + 4 : IMG_W - 1;

    auto fold = [&](int t, float* rm, float* cvo) {
        const float* Lr = &lds[t * 1024];
        float4 v   = *reinterpret_cast<const float4*>(Lr + j0);
        float  lf0 = Lr[jl];
        float  rg0 = Lr[jr];
        float  lf  = hasL ? lf0 : 0.f;
        float  rg  = hasR ? rg0 : 0.f;
        rm[0] = fminf(lf,  fminf(v.x, v.y));
        rm[1] = fminf(v.x, fminf(v.y, v.z));
        rm[2] = fminf(v.y, fminf(v.z, v.w));
        rm[3] = fminf(v.z, fminf(v.w, rg));
        cvo[0] = v.x; cvo[1] = v.y; cvo[2] = v.z; cvo[3] = v.w;
    };

    float l2[2]  = {0.f, 0.f}, xt[2] = {0.f, 0.f};
    float itr[2] = {0.f, 0.f}, sp[2] = {0.f, 0.f};
    int st = 0;

    auto px = [&](float x, float btv, float b2v, int a) {
        float f = fmaf(w0, btv, b2v);
        bool  c = f > 0.1f;
        st += (int)__popcll(__ballot(c));
        float u   = __builtin_amdgcn_exp2f(x * LOG2E);   // e^x
        float opu = 1.f + u;
        float p   = u * __builtin_amdgcn_rcpf(opu);      // sigmoid(x)
        l2[a]  += __builtin_amdgcn_logf(opu);            // log2(1+e^x)
        sp[a]  += p;
        xt[a]  += c ? x : 0.f;
        itr[a] += c ? p : 0.f;
    };

    // ---- rolling 4-row rm window over 4 row-pairs (all static after unroll)
    float rm0[4], rm1[4], rm2[4], rm3[4], cvA[4], cvB[4], cvC[4], tmp[4];
    fold(0, rm0, tmp);
    if (r0 == 0) { rm0[0] = rm0[1] = rm0[2] = rm0[3] = 0.f; }   // top pad row
    fold(1, rm1, cvA);
    float wb4A = 0.f, wb4B = 0.f;

    #pragma unroll
    for (int rp = 0; rp < 4; ++rp) {
        fold(2 * rp + 2, rm2, cvB);
        fold(2 * rp + 3, rm3, cvC);
        if (rp == 3 && r0 == IMG_H - 8) {                        // bottom pad row
            rm3[0] = rm3[1] = rm3[2] = rm3[3] = 0.f;
        }

        // bt rows 2rp, 2rp+1: bt = (g == 1) && (min3x3 == 0)
        float bta[4], btb[4];
        #pragma unroll
        for (int k = 0; k < 4; ++k) {
            float cma = fminf(rm0[k], fminf(rm1[k], rm2[k]));
            float cmb = fminf(rm1[k], fminf(rm2[k], rm3[k]));
            bta[k] = (cvA[k] > 0.5f && cma < 0.5f) ? 1.f : 0.f;
            btb[k] = (cvB[k] > 0.5f && cmb < 0.5f) ? 1.f : 0.f;
        }
        // bt4 centers: (r0, j0) for rows 0-3, (r0+4, j0) for rows 4-7
        if (rp == 0) wb4A = w2 * bta[0];
        if (rp == 2) wb4B = w2 * bta[0];
        const float wb  = (rp < 2) ? wb4A : wb4B;
        // bt2 sample row = 2rp (=bta), cols j0 / j0+2
        const float b20 = fmaf(w1, bta[0], wb);
        const float b21 = fmaf(w1, bta[2], wb);

        px(xv[2 * rp].x,     bta[0], b20, 0);
        px(xv[2 * rp].y,     bta[1], b20, 0);
        px(xv[2 * rp].z,     bta[2], b21, 0);
        px(xv[2 * rp].w,     bta[3], b21, 0);
        px(xv[2 * rp + 1].x, btb[0], b20, 1);
        px(xv[2 * rp + 1].y, btb[1], b20, 1);
        px(xv[2 * rp + 1].z, btb[2], b21, 1);
        px(xv[2 * rp + 1].w, btb[3], b21, 1);

        #pragma unroll
        for (int k = 0; k < 4; ++k) {
            rm0[k] = rm2[k]; rm1[k] = rm3[k]; cvA[k] = cvC[k];
        }
    }

    float bce   = fmaf(LN2, l2[0] + l2[1], -(xt[0] + xt[1]));
    float inter = itr[0] + itr[1];
    float sump  = sp[0] + sp[1];

    // wave64 reduce (st already wave-uniform via ballot)
    #pragma unroll
    for (int off = 32; off > 0; off >>= 1) {
        bce   += __shfl_down(bce, off);
        inter += __shfl_down(inter, off);
        sump  += __shfl_down(sump, off);
    }
    __syncthreads();            // all LDS mask reads done -> safe to reuse lds
    if (lane == 0) {
        lds[wid]      = bce;
        lds[4 + wid]  = inter;
        lds[8 + wid]  = sump;
        lds[12 + wid] = (float)st;
    }
    __syncthreads();
    if (tid == 0) {
        float4 o;
        o.x = (lds[0]  + lds[1])  + (lds[2]  + lds[3]);
        o.y = (lds[4]  + lds[5])  + (lds[6]  + lds[7]);
        o.z = (lds[8]  + lds[9])  + (lds[10] + lds[11]);
        o.w = (lds[12] + lds[13]) + (lds[14] + lds[15]);
        ws4[b] = o;
    }
}

// 1 block, 1024 threads. Thread t sums slots 2t, 2t+1; wave w (threads
// 64w..64w+63) covers slots [128w, 128w+128) == exactly image w.
__global__ __launch_bounds__(1024) void dal_finalize(
    const float4* __restrict__ ws4, float* __restrict__ out)
{
    const int t    = (int)threadIdx.x;
    const int wv   = t >> 6;      // wave id == image id
    const int lane = t & 63;

    float4 a = ws4[2 * t];
    float4 bq = ws4[2 * t + 1];
    float bce   = a.x + bq.x;
    float inter = a.y + bq.y;
    float sump  = a.z + bq.z;
    float sumt  = a.w + bq.w;

    #pragma unroll
    for (int off = 32; off > 0; off >>= 1) {
        bce   += __shfl_down(bce, off);
        inter += __shfl_down(inter, off);
        sump  += __shfl_down(sump, off);
        sumt  += __shfl_down(sumt, off);
    }

    __shared__ float sb[16], sd[16];
    if (lane == 0) {
        sb[wv] = bce;
        sd[wv] = 1.f - (2.f * inter + 1.f) / (sump + sumt + 1.f);
    }
    __syncthreads();
    if (t == 0) {
        float tb = 0.f, td = 0.f;
        #pragma unroll
        for (int i = 0; i < NIMG; ++i) { tb += sb[i]; td += sd[i]; }
        out[0] = tb / NPIX;
        out[1] = td / (float)NIMG;
    }
}

extern "C" void kernel_launch(void* const* d_in, const int* in_sizes, int n_in,
                              void* d_out, int out_size, void* d_ws, size_t ws_size,
                              hipStream_t stream)
{
    const float* x    = (const float*)d_in[0];  // boundary_logits [16,1,1024,1024]
    const float* g    = (const float*)d_in[1];  // gtmasks        [16,1024,1024]
    const float* fuse = (const float*)d_in[2];  // fuse_kernel    [3]
    float* out = (float*)d_out;
    float4* ws4 = (float4*)d_ws;

    dal_main<<<NBLK, 256, 0, stream>>>(x, g, fuse, ws4);
    dal_finalize<<<1, 1024, 0, stream>>>(ws4, out);
}

// Round 12
// 29.599 us; speedup vs baseline: 1.0842x; 1.0842x over previous
//
#include <hip/hip_runtime.h>

#define IMG_H 1024
#define IMG_W 1024
#define NIMG  16
#define NPIX  16777216.0f   // 16*1024*1024
#define NBLK  4096          // 256 4-row strips per image
#define LOG2E 1.44269504088896340736f
#define LN2   0.69314718055994530942f

#ifndef __has_builtin
#define __has_builtin(x) 0
#endif

// Async global->LDS, 16B per lane, zero VGPR cost. dstLds is the WAVE-UNIFORM
// base; HW adds lane*16. src is the per-lane global address.
__device__ __forceinline__ void stage16(const float* src, float* dstLds, int lane) {
#if __has_builtin(__builtin_amdgcn_global_load_lds)
    __builtin_amdgcn_global_load_lds(
        (const __attribute__((address_space(1))) void*)src,
        (__attribute__((address_space(3))) void*)dstLds,
        16, 0, 0);
#else
    *reinterpret_cast<float4*>(dstLds + (lane << 2)) =
        *reinterpret_cast<const float4*>(src);
#endif
}

// ws layout: one float4 per block {bce, inter, sum_p, sum_t}. 4096*16B = 64 KB.

__global__ __launch_bounds__(256, 6) void dal_main(
    const float* __restrict__ xlogits,
    const float* __restrict__ gmask,
    const float* __restrict__ fuse,
    float4* __restrict__ ws4)
{
    __shared__ float lds[6 * 1024];     // 24576 B: mask rows r0-1 .. r0+4

    // XCD-chunked swizzle (bijective, 4096 % 8 == 0): XCD x processes
    // contiguous strip-chunk [512x, 512x+512) -> halo rows shared via same-XCD L2.
    const int bid = blockIdx.x;
    const int b   = (bid & 7) * (NBLK / 8) + (bid >> 3);

    const int img  = b >> 8;            // 256 blocks per image
    const int r0   = (b & 255) << 2;    // rows r0 .. r0+3, r0 % 4 == 0
    const int tid  = (int)threadIdx.x;
    const int wid  = tid >> 6;
    const int lane = tid & 63;
    const int j0   = tid * 4;

    const float w0 = fuse[0], w1 = fuse[1], w2 = fuse[2];

    const size_t ibase = (size_t)img * (IMG_H * IMG_W);
    const float* gi = gmask + ibase;
    const float* xi = xlogits + ibase;

    // ---- stage ALL 6 mask rows async (no VGPR round trip; all in flight)
    #pragma unroll
    for (int t = 0; t < 6; ++t) {
        int r  = r0 - 1 + t;
        int rc = r < 0 ? 0 : (r > IMG_H - 1 ? IMG_H - 1 : r);  // clamp; pad fixed later
        stage16(gi + (size_t)rc * IMG_W + j0, &lds[t * 1024 + (wid << 8)], lane);
    }

    // ---- logits loads (registers; drained by the same barrier)
    float4 xv[4];
    const float* xr = xi + (size_t)r0 * IMG_W + j0;
    #pragma unroll
    for (int r = 0; r < 4; ++r)
        xv[r] = *reinterpret_cast<const float4*>(xr + (size_t)r * IMG_W);

    __syncthreads();   // vmcnt(0) + barrier: LDS tiles + xv resident

    // ---- fold rows from LDS: rowmin over (j0+k-1 .. j0+k+1) + center values
    const bool hasL = (j0 > 0);
    const bool hasR = (j0 + 4 < IMG_W);
    const int  jl   = hasL ? j0 - 1 : 0;
    const int  jr   = hasR ? j0 + 4 : IMG_W - 1;

    auto fold = [&](int t, float* rm, float* cvo) {
        const float* Lr = &lds[t * 1024];
        float4 v   = *reinterpret_cast<const float4*>(Lr + j0);
        float  lf0 = Lr[jl];
        float  rg0 = Lr[jr];
        float  lf  = hasL ? lf0 : 0.f;
        float  rg  = hasR ? rg0 : 0.f;
        rm[0] = fminf(lf,  fminf(v.x, v.y));
        rm[1] = fminf(v.x, fminf(v.y, v.z));
        rm[2] = fminf(v.y, fminf(v.z, v.w));
        rm[3] = fminf(v.z, fminf(v.w, rg));
        cvo[0] = v.x; cvo[1] = v.y; cvo[2] = v.z; cvo[3] = v.w;
    };

    float rm[6][4], cv[4][4], tmp[4];
    fold(0, rm[0], tmp);
    fold(1, rm[1], cv[0]);
    fold(2, rm[2], cv[1]);
    fold(3, rm[3], cv[2]);
    fold(4, rm[4], cv[3]);
    fold(5, rm[5], tmp);
    if (r0 == 0)         { rm[0][0] = rm[0][1] = rm[0][2] = rm[0][3] = 0.f; }
    if (r0 == IMG_H - 4) { rm[5][0] = rm[5][1] = rm[5][2] = rm[5][3] = 0.f; }

    // bt (stride-1 boundary map): bt = (g == 1) && (min3x3 == 0)
    float bt[4][4];
    #pragma unroll
    for (int r = 0; r < 4; ++r)
        #pragma unroll
        for (int k = 0; k < 4; ++k) {
            float cm = fminf(rm[r][k], fminf(rm[r + 1][k], rm[r + 2][k]));
            bt[r][k] = (cv[r][k] > 0.5f && cm < 0.5f) ? 1.f : 0.f;
        }

    // bt4 center = (r0, j0) = bt[0][0]; bt2 = bt(r0+(r&~1), j0+(k&~1))
    const float wb4 = w2 * bt[0][0];
    float base2[2][2];
    base2[0][0] = fmaf(w1, bt[0][0], wb4);
    base2[0][1] = fmaf(w1, bt[0][2], wb4);
    base2[1][0] = fmaf(w1, bt[2][0], wb4);
    base2[1][1] = fmaf(w1, bt[2][2], wb4);

    // Per-pixel: f = w0*bt + base2;  t = f > 0.1
    // bce_px = ln2*log2(1+e^x) - x*t ; p = u/(1+u), u = e^x
    // sum_t via ballot+popcount (SALU). Dual accumulators (row parity).
    float l2[2]  = {0.f, 0.f}, xt[2] = {0.f, 0.f};
    float itr[2] = {0.f, 0.f}, sp[2] = {0.f, 0.f};
    int st = 0;

    auto px = [&](float x, float btv, float b2v, int a) {
        float f = fmaf(w0, btv, b2v);
        bool  c = f > 0.1f;
        st += (int)__popcll(__ballot(c));
        float u   = __builtin_amdgcn_exp2f(x * LOG2E);   // e^x
        float opu = 1.f + u;
        float p   = u * __builtin_amdgcn_rcpf(opu);      // sigmoid(x)
        l2[a]  += __builtin_amdgcn_logf(opu);            // log2(1+e^x)
        sp[a]  += p;
        xt[a]  += c ? x : 0.f;
        itr[a] += c ? p : 0.f;
    };

    #pragma unroll
    for (int r = 0; r < 4; ++r) {
        const float bA = base2[r >> 1][0];
        const float bB = base2[r >> 1][1];
        px(xv[r].x, bt[r][0], bA, r & 1);
        px(xv[r].y, bt[r][1], bA, r & 1);
        px(xv[r].z, bt[r][2], bB, r & 1);
        px(xv[r].w, bt[r][3], bB, r & 1);
    }

    float bce   = fmaf(LN2, l2[0] + l2[1], -(xt[0] + xt[1]));
    float inter = itr[0] + itr[1];
    float sump  = sp[0] + sp[1];

    // wave64 reduce (st already wave-uniform via ballot)
    #pragma unroll
    for (int off = 32; off > 0; off >>= 1) {
        bce   += __shfl_down(bce, off);
        inter += __shfl_down(inter, off);
        sump  += __shfl_down(sump, off);
    }
    __syncthreads();            // all LDS mask reads done -> safe to reuse lds
    if (lane == 0) {
        lds[wid]      = bce;
        lds[4 + wid]  = inter;
        lds[8 + wid]  = sump;
        lds[12 + wid] = (float)st;
    }
    __syncthreads();
    if (tid == 0) {
        float4 o;
        o.x = (lds[0]  + lds[1])  + (lds[2]  + lds[3]);
        o.y = (lds[4]  + lds[5])  + (lds[6]  + lds[7]);
        o.z = (lds[8]  + lds[9])  + (lds[10] + lds[11]);
        o.w = (lds[12] + lds[13]) + (lds[14] + lds[15]);
        ws4[b] = o;
    }
}

// 1 block, 1024 threads. Thread t sums slots 4t..4t+3; wave w (threads
// 64w..64w+63) covers slots [256w, 256w+256) == exactly image w.
__global__ __launch_bounds__(1024) void dal_finalize(
    const float4* __restrict__ ws4, float* __restrict__ out)
{
    const int t    = (int)threadIdx.x;
    const int wv   = t >> 6;      // wave id == image id
    const int lane = t & 63;
    const int i0   = t * 4;

    float4 a = ws4[i0];
    float4 b = ws4[i0 + 1];
    float4 c = ws4[i0 + 2];
    float4 d = ws4[i0 + 3];
    float bce   = (a.x + b.x) + (c.x + d.x);
    float inter = (a.y + b.y) + (c.y + d.y);
    float sump  = (a.z + b.z) + (c.z + d.z);
    float sumt  = (a.w + b.w) + (c.w + d.w);

    #pragma unroll
    for (int off = 32; off > 0; off >>= 1) {
        bce   += __shfl_down(bce, off);
        inter += __shfl_down(inter, off);
        sump  += __shfl_down(sump, off);
        sumt  += __shfl_down(sumt, off);
    }

    __shared__ float sb[16], sd[16];
    if (lane == 0) {
        sb[wv] = bce;
        sd[wv] = 1.f - (2.f * inter + 1.f) / (sump + sumt + 1.f);
    }
    __syncthreads();
    if (t == 0) {
        float tb = 0.f, td = 0.f;
        #pragma unroll
        for (int i = 0; i < NIMG; ++i) { tb += sb[i]; td += sd[i]; }
        out[0] = tb / NPIX;
        out[1] = td / (float)NIMG;
    }
}

extern "C" void kernel_launch(void* const* d_in, const int* in_sizes, int n_in,
                              void* d_out, int out_size, void* d_ws, size_t ws_size,
                              hipStream_t stream)
{
    const float* x    = (const float*)d_in[0];  // boundary_logits [16,1,1024,1024]
    const float* g    = (const float*)d_in[1];  // gtmasks        [16,1024,1024]
    const float* fuse = (const float*)d_in[2];  // fuse_kernel    [3]
    float* out = (float*)d_out;
    float4* ws4 = (float4*)d_ws;

    dal_main<<<NBLK, 256, 0, stream>>>(x, g, fuse, ws4);
    dal_finalize<<<1, 1024, 0, stream>>>(ws4, out);
}